// Round 11
// baseline (473.287 us; speedup 1.0000x reference)
//
#include <hip/hip_runtime.h>
#include <hip/hip_cooperative_groups.h>
namespace cg = cooperative_groups;

// Problem constants (AttentionalCopula)
constexpr int kB = 16, kD = 256, kNH = 512, kNV = 256, kW = 768;
constexpr int kL = 4, kH = 8, kA = 64, kHA = 512, kM = 512, kR = 128;
constexpr int kKP = 288;  // K=257 zero-padded to multiple of 32
constexpr int kRows = kB * kNV;  // 4096

typedef __bf16 bf16x8 __attribute__((ext_vector_type(8)));
typedef __bf16 bf16x4 __attribute__((ext_vector_type(4)));
typedef float f32x4 __attribute__((ext_vector_type(4)));

__device__ inline void load_lds16(const __bf16* g, __bf16* l) {
  __builtin_amdgcn_global_load_lds(
      (const __attribute__((address_space(1))) void*)g,
      (__attribute__((address_space(3))) void*)l, 16, 0, 0);
}

// ---------------- merged prep kernel (1 launch) ----------------
constexpr int kP1 = kB * kW * kKP;        // ki
constexpr int kP2 = 4096 * kKP;           // kv weights
constexpr int kP3 = 12 * 512 * 512;       // ff weights
constexpr int kP4 = 200704;               // ds_wt, de_wt, kvb
constexpr int kP5 = 16;                   // zero d_out
constexpr int kPT = kP1 + kP2 + kP3 + kP4 + kP5;

__global__ void prep_kernel(const float* __restrict__ hist,
                            const float* __restrict__ hist_u,
                            const float* __restrict__ pred,
                            const float* __restrict__ pred_u,
                            const float* __restrict__ kw,
                            const float* __restrict__ vw,
                            const float* __restrict__ w1,
                            const float* __restrict__ w2,
                            const float* __restrict__ w3,
                            const float* __restrict__ ds_w,
                            const float* __restrict__ de_w,
                            const float* __restrict__ key_b,
                            const float* __restrict__ val_b,
                            __bf16* __restrict__ ki,
                            __bf16* __restrict__ kvwt,
                            __bf16* __restrict__ ffwt,
                            __bf16* __restrict__ ds_wt,
                            __bf16* __restrict__ de_wt,
                            float* __restrict__ kvb,
                            float* __restrict__ outz) {
  int i = blockIdx.x * 256 + threadIdx.x;
  if (i < kP1) {
    int d = i % kKP;
    int bw = i / kKP;
    int w = bw % kW;
    int b = bw / kW;
    float v = 0.f;
    if (d < 257) {
      if (w < kNH)
        v = (d < kD) ? hist[((size_t)b * kNH + w) * kD + d] : hist_u[b * kNH + w];
      else {
        int p = w - kNH;
        v = (d < kD) ? pred[((size_t)b * kNV + p) * kD + d] : pred_u[b * kNV + p];
      }
    }
    ki[i] = (__bf16)v;
  } else if (i < kP1 + kP2) {
    int j = i - kP1;
    int d = j % kKP;
    int c = j / kKP;
    float v = 0.f;
    if (d < 257) {
      bool isv = c >= 2048;
      int cc = isv ? c - 2048 : c;
      int l = cc >> 9, rest = cc & 511;
      int h = rest >> 6, a = rest & 63;
      size_t src = (((size_t)l * kH + h) * 257 + d) * kA + a;
      v = isv ? vw[src] : kw[src];
    }
    kvwt[j] = (__bf16)v;
  } else if (i < kP1 + kP2 + kP3) {
    int j = i - kP1 - kP2;
    int k = j & 511;
    int n = (j >> 9) & 511;
    int mat = j >> 18;
    int l = mat / 3, which = mat % 3;
    const float* src = which == 0 ? w1 : which == 1 ? w2 : w3;
    ffwt[j] = (__bf16)src[((size_t)l * 512 + k) * 512 + n];
  } else if (i < kP1 + kP2 + kP3 + kP4) {
    int j = i - kP1 - kP2 - kP3;
    if (j < 131072) {
      int n = j >> 8, k = j & 255;
      ds_wt[j] = (__bf16)ds_w[k * 512 + n];
    } else if (j < 196608) {
      int jj = j - 131072;
      int n = jj >> 9, k = jj & 511;
      de_wt[jj] = (__bf16)de_w[k * 128 + n];
    } else {
      int c = j - 196608;  // 0..4095
      bool isv = c >= 2048;
      int cc = isv ? c - 2048 : c;
      int l = cc >> 9, rest = cc & 511;
      kvb[c] = isv ? val_b[l * 512 + rest] : key_b[l * 512 + rest];
    }
  } else if (i < kPT) {
    outz[i - kP1 - kP2 - kP3 - kP4] = 0.f;
  }
}

// ---------------- generic bf16 MFMA GEMM core ----------------
template <int BN, int OMODE, bool RELU, bool KIMAP, bool BIASROW>
__device__ __forceinline__ void gemm_core(
    int bxv, int byv, const __bf16* __restrict__ A,
    const __bf16* __restrict__ Bt, const float* __restrict__ bias,
    void* __restrict__ Cout, __bf16* __restrict__ Cout2, int K, int lda,
    int ldc, __bf16* As, __bf16* Bs) {
  constexpr int JN = BN / 32;
  constexpr int BROWS = BN / 4;
  const int t = threadIdx.x;
  const int wid = t >> 6;
  const int lane = t & 63;
  const int bm = byv * 128;
  const int bn = bxv * BN;
  const int wm = (wid >> 1) * 64;
  const int wn = (wid & 1) * (BN / 2);
  const int sr = lane >> 2, sc = lane & 3;
  const int skey = (sr >> 1) & 3;
  const int abase = KIMAP ? ((bm >> 8) * 768 + 512 + (bm & 255)) : bm;
  const __bf16* Ag = A + (size_t)(abase + wid * 32 + sr) * lda + (sc ^ skey) * 8;
  const __bf16* Bg = Bt + (size_t)(bn + wid * BROWS + sr) * K + (sc ^ skey) * 8;
  __bf16* AsW = As + (wid * 32) * 32;
  __bf16* BsW = Bs + (wid * BROWS) * 32;

  f32x4 acc[4][JN] = {};
  const int q = lane >> 4, mr = lane & 15;
  const int rkey = (mr >> 1) & 3;
  for (int k0 = 0; k0 < K; k0 += 32) {
    if (k0) __syncthreads();
    load_lds16(Ag + k0, AsW);
    load_lds16(Ag + (size_t)16 * lda + k0, AsW + 16 * 32);
    load_lds16(Bg + k0, BsW);
    if (BN == 128) load_lds16(Bg + (size_t)16 * K + k0, BsW + 16 * 32);
    __syncthreads();
    bf16x8 af[4], bfr[JN];
#pragma unroll
    for (int i = 0; i < 4; ++i)
      af[i] = *(const bf16x8*)(As + (wm + i * 16 + mr) * 32 + (q ^ rkey) * 8);
#pragma unroll
    for (int j = 0; j < JN; ++j)
      bfr[j] = *(const bf16x8*)(Bs + (wn + j * 16 + mr) * 32 + (q ^ rkey) * 8);
#pragma unroll
    for (int i = 0; i < 4; ++i)
#pragma unroll
      for (int j = 0; j < JN; ++j)
        acc[i][j] = __builtin_amdgcn_mfma_f32_16x16x32_bf16(af[i], bfr[j],
                                                            acc[i][j], 0, 0, 0);
  }
#pragma unroll
  for (int j = 0; j < JN; ++j) {
    int col = bn + wn + j * 16 + mr;
    float bscol = BIASROW ? 0.f : bias[col];
#pragma unroll
    for (int i = 0; i < 4; ++i) {
      int row0 = bm + wm + i * 16 + q * 4;
#pragma unroll
      for (int r = 0; r < 4; ++r) {
        float v = acc[i][j][r] + (BIASROW ? bias[row0 + r] : bscol);
        if (RELU) v = fmaxf(v, 0.f);
        size_t idx = (size_t)(row0 + r) * ldc + col;
        if (OMODE == 0) {
          ((float*)Cout)[idx] = v;
        } else if (OMODE == 1) {
          ((__bf16*)Cout)[idx] = (__bf16)v;
        } else {
          ((float*)Cout)[idx] = v;
          Cout2[idx] = (__bf16)v;
        }
      }
    }
  }
}

// ---------------- fused ds + keys + vT GEMM (one launch, 3328 blocks) ----------------
__global__ __launch_bounds__(256) void gemm3_kernel(
    const __bf16* __restrict__ ki, const __bf16* __restrict__ ds_wt,
    const float* __restrict__ ds_b, float* __restrict__ att,
    __bf16* __restrict__ att_bf, const __bf16* __restrict__ kv_wt,
    const float* __restrict__ kvb, __bf16* __restrict__ kvs_k,
    __bf16* __restrict__ vT) {
  __shared__ __align__(16) __bf16 smem[8192];
  __bf16* As = smem;
  __bf16* Bs = smem + 4096;
  int bid = blockIdx.x;
  if (bid < 256) {
    gemm_core<64, 2, false, true, false>(bid & 7, bid >> 3, ki, ds_wt, ds_b,
                                         att, att_bf, 256, kKP, 512, As, Bs);
  } else if (bid < 1792) {
    int b2 = bid - 256;
    gemm_core<128, 1, false, false, false>(b2 & 15, b2 >> 4, ki, kv_wt, kvb,
                                           kvs_k, nullptr, kKP, kKP, 2048, As,
                                           Bs);
  } else {
    int b3 = bid - 1792;
    gemm_core<128, 1, false, false, true>(b3 % 96, b3 / 96,
                                          kv_wt + (size_t)2048 * kKP, ki,
                                          kvb + 2048, vT, nullptr, kKP, kKP,
                                          12288, As, Bs);
  }
}

// ---------------- stage: MFMA flash attention (S^T variant); u in [0,512) ----------------
__device__ __forceinline__ void attn_stage(
    int u, __bf16* smem, const __bf16* __restrict__ attbf,
    const __bf16* __restrict__ kvs_k, const __bf16* __restrict__ vT,
    __bf16* __restrict__ outbf, int l) {
  const int qt = u & 3, h = (u >> 2) & 7, b = u >> 5;
  __bf16* Ks = smem;
  __bf16* Vt = smem + 64 * 72;
  __bf16* Ps = smem + 2 * 64 * 72;
  const int t = threadIdx.x;
  const int w = t >> 6, lane = t & 63;
  const int quad = lane >> 4, mr = lane & 15;
  bf16x8 aq[2];
  {
    const __bf16* qp = attbf + ((size_t)(b * kNV + qt * 64 + w * 16 + mr) * kHA +
                                h * kA + quad * 8);
    aq[0] = *(const bf16x8*)qp;
    aq[1] = *(const bf16x8*)(qp + 32);
  }
  f32x4 o[4] = {};
  float m_ = -1e30f, l_ = 0.f;
  const int cmax = kNH + qt * 64;
  const int pr = t >> 2, pc = t & 3;
  const __bf16* kbase = kvs_k + ((size_t)(b * kW + pr) * 2048 + l * 512 + h * kA);
  const __bf16* vbase = vT + (size_t)(l * 512 + h * kA + pr) * 12288 + b * kW;
  bf16x8 kc0, kc1, vc0, vc1;
  kc0 = *(const bf16x8*)(kbase + pc * 8);
  kc1 = *(const bf16x8*)(kbase + pc * 8 + 32);
  vc0 = *(const bf16x8*)(vbase + pc * 16);
  vc1 = *(const bf16x8*)(vbase + pc * 16 + 8);
  for (int c0 = 0; c0 <= cmax; c0 += 64) {
    __syncthreads();
    *(bf16x8*)&Ks[pr * 72 + pc * 8] = kc0;
    *(bf16x8*)&Ks[pr * 72 + pc * 8 + 32] = kc1;
    *(bf16x8*)&Vt[pr * 72 + pc * 16] = vc0;
    *(bf16x8*)&Vt[pr * 72 + pc * 16 + 8] = vc1;
    __syncthreads();
    if (c0 + 64 <= cmax) {
      const __bf16* kp = kbase + (size_t)(c0 + 64) * 2048;
      const __bf16* vp = vbase + c0 + 64;
      kc0 = *(const bf16x8*)(kp + pc * 8);
      kc1 = *(const bf16x8*)(kp + pc * 8 + 32);
      vc0 = *(const bf16x8*)(vp + pc * 16);
      vc1 = *(const bf16x8*)(vp + pc * 16 + 8);
    }
    f32x4 s[4];
#pragma unroll
    for (int j = 0; j < 4; ++j) {
      bf16x8 ak0 = *(const bf16x8*)&Ks[(j * 16 + mr) * 72 + quad * 8];
      bf16x8 ak1 = *(const bf16x8*)&Ks[(j * 16 + mr) * 72 + quad * 8 + 32];
      f32x4 z = {};
      z = __builtin_amdgcn_mfma_f32_16x16x32_bf16(ak0, aq[0], z, 0, 0, 0);
      z = __builtin_amdgcn_mfma_f32_16x16x32_bf16(ak1, aq[1], z, 0, 0, 0);
      s[j] = z;
    }
    const int lim = cmax - c0;
    float sv[16], mx = -1e30f;
#pragma unroll
    for (int j = 0; j < 4; ++j)
#pragma unroll
      for (int r = 0; r < 4; ++r) {
        int p = j * 16 + quad * 4 + r;
        float x = (p < lim + mr) ? s[j][r] * 0.125f : -1e30f;
        sv[j * 4 + r] = x;
        mx = fmaxf(mx, x);
      }
    mx = fmaxf(mx, __shfl_xor(mx, 16));
    mx = fmaxf(mx, __shfl_xor(mx, 32));
    float mnew = fmaxf(m_, mx);
    float corr = __expf(m_ - mnew);
    float rs = 0.f;
#pragma unroll
    for (int i = 0; i < 16; ++i) {
      sv[i] = __expf(sv[i] - mnew);
      rs += sv[i];
    }
    rs += __shfl_xor(rs, 16);
    rs += __shfl_xor(rs, 32);
    l_ = l_ * corr + rs;
    m_ = mnew;
#pragma unroll
    for (int j = 0; j < 4; ++j) {
      bf16x4 pk = {(__bf16)sv[j * 4 + 0], (__bf16)sv[j * 4 + 1],
                   (__bf16)sv[j * 4 + 2], (__bf16)sv[j * 4 + 3]};
      *(bf16x4*)&Ps[(w * 16 + mr) * 72 + j * 16 + quad * 4] = pk;
    }
#pragma unroll
    for (int r = 0; r < 4; ++r) {
      float cr = __shfl(corr, quad * 4 + r);
#pragma unroll
      for (int j = 0; j < 4; ++j) o[j][r] *= cr;
    }
    bf16x8 ap0 = *(const bf16x8*)&Ps[(w * 16 + mr) * 72 + quad * 8];
    bf16x8 ap1 = *(const bf16x8*)&Ps[(w * 16 + mr) * 72 + quad * 8 + 32];
#pragma unroll
    for (int j = 0; j < 4; ++j) {
      bf16x8 b0 = *(const bf16x8*)&Vt[(j * 16 + mr) * 72 + quad * 8];
      bf16x8 b1 = *(const bf16x8*)&Vt[(j * 16 + mr) * 72 + quad * 8 + 32];
      o[j] = __builtin_amdgcn_mfma_f32_16x16x32_bf16(ap0, b0, o[j], 0, 0, 0);
      o[j] = __builtin_amdgcn_mfma_f32_16x16x32_bf16(ap1, b1, o[j], 0, 0, 0);
    }
  }
  float invl = 1.f / l_;
#pragma unroll
  for (int r = 0; r < 4; ++r) {
    float ir = __shfl(invl, quad * 4 + r);
    int row = b * kNV + qt * 64 + w * 16 + quad * 4 + r;
#pragma unroll
    for (int j = 0; j < 4; ++j)
      outbf[(size_t)row * kHA + h * kA + j * 16 + mr] = (__bf16)(o[j][r] * ir);
  }
}

// ---------------- stage: att = LN(att + add_bf); wave-per-row; u in [0,512) ----------------
__device__ __forceinline__ void ln_stage(int u, float* __restrict__ att,
                                         const __bf16* __restrict__ addbf,
                                         const float* __restrict__ g,
                                         const float* __restrict__ be,
                                         __bf16* __restrict__ attbf) {
  const int t = threadIdx.x;
  const int wid = t >> 6, lane = t & 63;
#pragma unroll
  for (int i = 0; i < 2; ++i) {
    int row = u * 8 + wid * 2 + i;
    float* ar = att + (size_t)row * kHA + lane * 8;
    float4 x0 = *(float4*)ar;
    float4 x1 = *(float4*)(ar + 4);
    bf16x8 d = *(const bf16x8*)(addbf + (size_t)row * kHA + lane * 8);
    float xs[8] = {x0.x + (float)d[0], x0.y + (float)d[1], x0.z + (float)d[2],
                   x0.w + (float)d[3], x1.x + (float)d[4], x1.y + (float)d[5],
                   x1.z + (float)d[6], x1.w + (float)d[7]};
    float s = 0.f, sq = 0.f;
#pragma unroll
    for (int e = 0; e < 8; ++e) {
      s += xs[e];
      sq += xs[e] * xs[e];
    }
    for (int o = 32; o; o >>= 1) {
      s += __shfl_xor(s, o);
      sq += __shfl_xor(sq, o);
    }
    float mean = s * (1.f / kHA);
    float inv = rsqrtf(sq * (1.f / kHA) - mean * mean + 1e-5f);
    const float* gp = g + lane * 8;
    const float* bp = be + lane * 8;
    float4 g0 = *(const float4*)gp, g1 = *(const float4*)(gp + 4);
    float4 b0 = *(const float4*)bp, b1 = *(const float4*)(bp + 4);
    float ga[8] = {g0.x, g0.y, g0.z, g0.w, g1.x, g1.y, g1.z, g1.w};
    float ba[8] = {b0.x, b0.y, b0.z, b0.w, b1.x, b1.y, b1.z, b1.w};
    float ys[8];
    bf16x8 yb;
#pragma unroll
    for (int e = 0; e < 8; ++e) {
      ys[e] = ga[e] * (xs[e] - mean) * inv + ba[e];
      yb[e] = (__bf16)ys[e];
    }
    *(float4*)ar = make_float4(ys[0], ys[1], ys[2], ys[3]);
    *(float4*)(ar + 4) = make_float4(ys[4], ys[5], ys[6], ys[7]);
    *(bf16x8*)(attbf + (size_t)row * kHA + lane * 8) = yb;
  }
}

// ---------------- stage: de-projection + loss (atomic into out); u in [0,64) ----------------
__device__ __forceinline__ void de_loss_stage(
    int blk, float* red, const __bf16* __restrict__ attbf,
    const __bf16* __restrict__ de_wt, const float* __restrict__ de_b,
    const float* __restrict__ pred_u, float* __restrict__ out) {
  const int t = threadIdx.x;
  const int w = t >> 6, lane = t & 63, quad = lane >> 4, mr = lane & 15;
  const int row0 = blk * 64 + w * 16;
  f32x4 acc[8] = {};
  const __bf16* Ap = attbf + (size_t)(row0 + mr) * kHA + quad * 8;
#pragma unroll 4
  for (int k0 = 0; k0 < 512; k0 += 32) {
    bf16x8 a = *(const bf16x8*)(Ap + k0);
#pragma unroll
    for (int j = 0; j < 8; ++j) {
      bf16x8 bb =
          *(const bf16x8*)(de_wt + (size_t)(j * 16 + mr) * 512 + k0 + quad * 8);
      acc[j] = __builtin_amdgcn_mfma_f32_16x16x32_bf16(a, bb, acc[j], 0, 0, 0);
    }
  }
  float dbv[8];
#pragma unroll
  for (int j = 0; j < 8; ++j) dbv[j] = de_b[j * 16 + mr];
  float lpacc = 0.f;
#pragma unroll
  for (int r = 0; r < 4; ++r) {
    int row = row0 + quad * 4 + r;
    int v = row & 255;
    float lg[8], mx = -1e30f;
#pragma unroll
    for (int j = 0; j < 8; ++j) {
      lg[j] = acc[j][r] + dbv[j];
      mx = fmaxf(mx, lg[j]);
    }
    mx = fmaxf(mx, __shfl_xor(mx, 1));
    mx = fmaxf(mx, __shfl_xor(mx, 2));
    mx = fmaxf(mx, __shfl_xor(mx, 4));
    mx = fmaxf(mx, __shfl_xor(mx, 8));
    float se = 0.f;
#pragma unroll
    for (int j = 0; j < 8; ++j) se += __expf(lg[j] - mx);
    se += __shfl_xor(se, 1);
    se += __shfl_xor(se, 2);
    se += __shfl_xor(se, 4);
    se += __shfl_xor(se, 8);
    float lse = mx + __logf(se);
    float u = pred_u[(row >> 8) * 256 + v];
    int tgt = (int)floorf(u * 128.f);
    tgt = max(0, min(127, tgt));
    float cand = (mr == (tgt & 15)) ? lg[tgt >> 4] : 0.f;
    cand += __shfl_xor(cand, 1);
    cand += __shfl_xor(cand, 2);
    cand += __shfl_xor(cand, 4);
    cand += __shfl_xor(cand, 8);
    float lp = (v >= 1) ? (4.8520302639196171f + cand - lse) : 0.f;  // ln(128)
    lpacc += lp;
  }
  lpacc += __shfl_xor(lpacc, 16);
  lpacc += __shfl_xor(lpacc, 32);
  __syncthreads();
  if (lane == 0) red[w] = lpacc;
  __syncthreads();
  if (t == 0)
    atomicAdd(&out[blk >> 2], -(red[0] + red[1] + red[2] + red[3]));
}

// ---------------- standalone kernels (stream fallback path) ----------------
__global__ __launch_bounds__(256) void attn_kernel(
    const __bf16* __restrict__ attbf, const __bf16* __restrict__ kvs_k,
    const __bf16* __restrict__ vT, __bf16* __restrict__ outbf, int l) {
  __shared__ __align__(16) __bf16 smem[3 * 64 * 72];
  attn_stage(blockIdx.x, smem, attbf, kvs_k, vT, outbf, l);
}

__global__ __launch_bounds__(256) void ln_kernel(
    float* __restrict__ att, const __bf16* __restrict__ addbf,
    const float* __restrict__ g, const float* __restrict__ be,
    __bf16* __restrict__ attbf) {
  ln_stage(blockIdx.x, att, addbf, g, be, attbf);
}

template <bool RELU>
__global__ __launch_bounds__(256) void gemm_ff_kernel(
    const __bf16* __restrict__ A, const __bf16* __restrict__ Bt,
    const float* __restrict__ bias, __bf16* __restrict__ Cout) {
  __shared__ __align__(16) __bf16 smem[6144];
  gemm_core<64, 1, RELU, false, false>(blockIdx.x & 7, blockIdx.x >> 3, A, Bt,
                                       bias, Cout, nullptr, 512, 512, 512, smem,
                                       smem + 4096);
}

__global__ __launch_bounds__(256) void de_loss_kernel(
    const __bf16* __restrict__ attbf, const __bf16* __restrict__ de_wt,
    const float* __restrict__ de_b, const float* __restrict__ pred_u,
    float* __restrict__ out) {
  __shared__ float red[4];
  de_loss_stage(blockIdx.x, red, attbf, de_wt, de_b, pred_u, out);
}

// ---------------- whole 4-layer stack + loss: ONE cooperative kernel ----------------
__global__ __launch_bounds__(256, 2) void model_kernel(
    const __bf16* kvs_k, const __bf16* vT, float* att, __bf16* att_bf,
    __bf16* tmp_bf, __bf16* ff1_bf, __bf16* ff2_bf, const __bf16* ffw_t,
    const float* ff_b1, const float* ff_b2, const float* ff_b3,
    const float* ln1_g, const float* ln1_b, const float* ln2_g,
    const float* ln2_b, const __bf16* de_wt, const float* de_b,
    const float* pred_u, float* out) {
  cg::grid_group grid = cg::this_grid();
  __shared__ __align__(16) __bf16 smem[3 * 64 * 72];  // 27.6 KB
  const int bid = blockIdx.x;
  for (int l = 0; l < kL; ++l) {
    attn_stage(bid, smem, att_bf, kvs_k, vT, tmp_bf, l);
    grid.sync();
    ln_stage(bid, att, tmp_bf, ln1_g + l * kHA, ln1_b + l * kHA, att_bf);
    grid.sync();
    if (bid < 256)
      gemm_core<64, 1, true, false, false>(
          bid & 7, bid >> 3, att_bf, ffw_t + (size_t)(l * 3) * 262144,
          ff_b1 + l * kM, ff1_bf, nullptr, 512, 512, 512, smem, smem + 4096);
    grid.sync();
    if (bid < 256)
      gemm_core<64, 1, true, false, false>(
          bid & 7, bid >> 3, ff1_bf, ffw_t + (size_t)(l * 3 + 1) * 262144,
          ff_b2 + l * kM, ff2_bf, nullptr, 512, 512, 512, smem, smem + 4096);
    grid.sync();
    if (bid < 256)
      gemm_core<64, 1, false, false, false>(
          bid & 7, bid >> 3, ff2_bf, ffw_t + (size_t)(l * 3 + 2) * 262144,
          ff_b3 + l * kHA, tmp_bf, nullptr, 512, 512, 512, smem, smem + 4096);
    grid.sync();
    ln_stage(bid, att, tmp_bf, ln2_g + l * kHA, ln2_b + l * kHA, att_bf);
    grid.sync();
  }
  if (bid < 64)
    de_loss_stage(bid, (float*)smem, att_bf, de_wt, de_b, pred_u, out);
}

extern "C" void kernel_launch(void* const* d_in, const int* in_sizes, int n_in,
                              void* d_out, int out_size, void* d_ws, size_t ws_size,
                              hipStream_t stream) {
  const float* hist   = (const float*)d_in[0];
  const float* hist_u = (const float*)d_in[1];
  const float* pred   = (const float*)d_in[2];
  const float* pred_u = (const float*)d_in[3];
  const float* ds_w   = (const float*)d_in[4];
  const float* ds_b   = (const float*)d_in[5];
  const float* key_w  = (const float*)d_in[6];
  const float* key_b  = (const float*)d_in[7];
  const float* val_w  = (const float*)d_in[8];
  const float* val_b  = (const float*)d_in[9];
  const float* ln1_g  = (const float*)d_in[10];
  const float* ln1_b  = (const float*)d_in[11];
  const float* ln2_g  = (const float*)d_in[12];
  const float* ln2_b  = (const float*)d_in[13];
  const float* ff_w1  = (const float*)d_in[14];
  const float* ff_b1  = (const float*)d_in[15];
  const float* ff_w2  = (const float*)d_in[16];
  const float* ff_b2  = (const float*)d_in[17];
  const float* ff_w3  = (const float*)d_in[18];
  const float* ff_b3  = (const float*)d_in[19];
  const float* de_w   = (const float*)d_in[20];
  const float* de_b   = (const float*)d_in[21];
  float* out = (float*)d_out;

  char* ws = (char*)d_ws;
  size_t off = 0;
  auto alloc = [&](size_t bytes) { char* p = ws + off; off += bytes; return p; };
  __bf16* ki_bf  = (__bf16*)alloc((size_t)kB * kW * kKP * 2);       // 7.1 MB
  __bf16* kv_wt  = (__bf16*)alloc((size_t)4096 * kKP * 2);          // 2.4 MB
  __bf16* ffw_t  = (__bf16*)alloc((size_t)12 * 512 * 512 * 2);      // 6.3 MB
  __bf16* ds_wt  = (__bf16*)alloc((size_t)512 * 256 * 2);
  __bf16* de_wt  = (__bf16*)alloc((size_t)128 * 512 * 2);
  float*  kvb    = (float*)alloc((size_t)4096 * 4);
  __bf16* kvs_k  = (__bf16*)alloc((size_t)kB * kW * 2048 * 2);      // 50.3 MB
  __bf16* vT     = (__bf16*)alloc((size_t)2048 * 12288 * 2);        // 50.3 MB
  float*  att    = (float*)alloc((size_t)kRows * kHA * 4);          // 8.4 MB
  __bf16* att_bf = (__bf16*)alloc((size_t)kRows * kHA * 2);
  __bf16* tmp_bf = (__bf16*)alloc((size_t)kRows * kHA * 2);
  __bf16* ff1_bf = (__bf16*)alloc((size_t)kRows * kM * 2);
  __bf16* ff2_bf = (__bf16*)alloc((size_t)kRows * kM * 2);

  prep_kernel<<<(kPT + 255) / 256, 256, 0, stream>>>(
      hist, hist_u, pred, pred_u, key_w, val_w, ff_w1, ff_w2, ff_w3, ds_w, de_w,
      key_b, val_b, ki_bf, kv_wt, ffw_t, ds_wt, de_wt, kvb, out);

  gemm3_kernel<<<3328, 256, 0, stream>>>(ki_bf, ds_wt, ds_b, att, att_bf, kv_wt,
                                         kvb, kvs_k, vT);

  // Cooperative path only if the runtime says 512 blocks are co-residentable.
  int nbPerCU = 0;
  hipError_t qerr = hipOccupancyMaxActiveBlocksPerMultiprocessor(
      &nbPerCU, (const void*)model_kernel, 256, 0);
  bool coop = (qerr == hipSuccess && nbPerCU >= 2);
  if (coop) {
    void* cargs[] = {(void*)&kvs_k,  (void*)&vT,     (void*)&att,
                     (void*)&att_bf, (void*)&tmp_bf, (void*)&ff1_bf,
                     (void*)&ff2_bf, (void*)&ffw_t,  (void*)&ff_b1,
                     (void*)&ff_b2,  (void*)&ff_b3,  (void*)&ln1_g,
                     (void*)&ln1_b,  (void*)&ln2_g,  (void*)&ln2_b,
                     (void*)&de_wt,  (void*)&de_b,   (void*)&pred_u,
                     (void*)&out};
    hipError_t lerr = hipLaunchCooperativeKernel(
        (void*)model_kernel, dim3(512), dim3(256), cargs, 0, stream);
    if (lerr != hipSuccess) coop = false;
  }
  if (!coop) {
    for (int l = 0; l < kL; ++l) {
      attn_kernel<<<512, 256, 0, stream>>>(att_bf, kvs_k, vT, tmp_bf, l);
      ln_kernel<<<512, 256, 0, stream>>>(att, tmp_bf, ln1_g + l * kHA,
                                         ln1_b + l * kHA, att_bf);
      gemm_ff_kernel<true><<<256, 256, 0, stream>>>(
          att_bf, ffw_t + (size_t)(l * 3) * 262144, ff_b1 + l * kM, ff1_bf);
      gemm_ff_kernel<true><<<256, 256, 0, stream>>>(
          ff1_bf, ffw_t + (size_t)(l * 3 + 1) * 262144, ff_b2 + l * kM, ff2_bf);
      gemm_ff_kernel<false><<<256, 256, 0, stream>>>(
          ff2_bf, ffw_t + (size_t)(l * 3 + 2) * 262144, ff_b3 + l * kHA, tmp_bf);
      ln_kernel<<<512, 256, 0, stream>>>(att, tmp_bf, ln2_g + l * kHA,
                                         ln2_b + l * kHA, att_bf);
    }
    de_loss_kernel<<<64, 256, 0, stream>>>(att_bf, de_wt, de_b, pred_u, out);
  }
}